// Round 7
// baseline (225.573 us; speedup 1.0000x reference)
//
#include <hip/hip_runtime.h>
#include <math.h>

#define HDIM 4096
#define NEXP 64
#define NTOK 8192
#define KSPLIT 16
#define KSLICE (HDIM / KSPLIT)   // 256
#define BM 128
#define CHUNK 32
#define NCHUNK (KSLICE / CHUNK)  // 8
#define AUXCOPIES 32             // auxbuf spread (32-way atomic contention)
#define AUXF (AUXCOPIES * 128)   // floats of auxbuf
#define TPW 2
#define TOPK_BLOCKS (NTOK / (4 * TPW))  // 1024

typedef short short8 __attribute__((ext_vector_type(8)));
typedef float f32x4 __attribute__((ext_vector_type(4)));
typedef const __attribute__((address_space(1))) unsigned int* gas_t;
typedef __attribute__((address_space(3))) unsigned int* las_t;

// Exact 3-way bf16 split of two fp32 values, packed as (lo16=x0, hi16=x1).
// x = hi + mid + lo exactly (8+8+8 mantissa bits covers fp32's 24).
__device__ __forceinline__ void split2x3(float x0, float x1, int& h, int& md, int& lo) {
  unsigned u0 = __float_as_uint(x0), u1 = __float_as_uint(x1);
  unsigned h0 = u0 & 0xFFFF0000u, h1 = u1 & 0xFFFF0000u;
  float r0 = x0 - __uint_as_float(h0);
  float r1 = x1 - __uint_as_float(h1);
  unsigned m0 = __float_as_uint(r0) & 0xFFFF0000u;
  unsigned m1 = __float_as_uint(r1) & 0xFFFF0000u;
  float s0 = r0 - __uint_as_float(m0);
  float s1 = r1 - __uint_as_float(m1);
  h  = (int)((h0 >> 16) | h1);
  md = (int)((m0 >> 16) | m1);
  lo = (int)((__float_as_uint(s0) >> 16) | (__float_as_uint(s1) & 0xFFFF0000u));
}

__device__ __forceinline__ short8 pack_s8(int a, int b, int c, int d) {
  union { int i[4]; short8 s; } u;
  u.i[0] = a; u.i[1] = b; u.i[2] = c; u.i[3] = d;
  return u.s;
}

// ---------------------------------------------------------------------------
// GEMM v5.1: BARRIER-FREE wave-private pipeline, vmcnt-order-correct.
// Index algebra: wave w's stageA DMA writes LDS rows [32w,32w+32) and its
// fragment reads touch exactly those rows -> no cross-wave LDS dependency;
// no s_barrier needed (v5 insight).
// v5.1 fix: vmcnt retires IN ISSUE ORDER, so v5's order (stageA before W
// loads) made the W dataflow wait drain the A-DMA mid-chunk. New issue order
// per chunk, pinned by sched_barrier(0):
//   vmcnt(0)[drains stageA(i)] -> [8 W loads + 4 ds_read_b128] ->
//   [stageA(i+1), stays in flight a full chunk] -> [splits + 48 MFMA;
//   compiler's W wait = vmcnt(4), leaves stageA outstanding].
// B conversion folded in (same fp32 values -> bit-identical logits).
// WAR ledger: buf^1 LDS reads at iter i-1 were lgkm-drained before their
// data use, which precedes stageA(i+1)'s issue in program order.
// Block (0,0) zeroes auxbuf.
// ---------------------------------------------------------------------------
__global__ __launch_bounds__(256, 4) void gemm_k(const float* __restrict__ A,
                                                 const float* __restrict__ W,
                                                 float* __restrict__ Lp,
                                                 float* __restrict__ auxbuf,
                                                 int atomic_mode) {
  __shared__ __align__(16) float As[2][BM * CHUNK];  // 2 x 16 KB
  const int tid = threadIdx.x;
  if (blockIdx.x == 0 && blockIdx.y == 0) {
#pragma unroll
    for (int t = tid; t < AUXF; t += 256) auxbuf[t] = 0.f;
  }
  const int m_base = blockIdx.x * BM;
  const int k_base = blockIdx.y * KSLICE;
  float* Lout = Lp + (atomic_mode ? (size_t)0 : (size_t)blockIdx.y * NTOK * NEXP);

  const int lane = tid & 63;
  const int wave = tid >> 6;
  const int l15 = lane & 15;
  const int quad = lane >> 4;
  const int wm = wave * 32;

  // --- A staging geometry (global_load_lds: lane l -> ldsbase + l*16B) ---
  // slot S=(wave*4+j)*64+lane holds row = S>>3 (= wave*32+j*8+(lane>>3)),
  // swizzled colblk sw = lane&7; global colblk c = sw ^ (row&7)
  const int rowp = wave * 32 + (lane >> 3);
  const int cblk = (lane & 7) ^ (lane >> 3);
  const float* gA0 = A + (size_t)(m_base + rowp) * HDIM + k_base + cblk * 4;

  auto stageA = [&](int i, int buf) {
#pragma unroll
    for (int j = 0; j < 4; ++j) {
      const float* src = gA0 + (size_t)(j * 8) * HDIM + i * CHUNK;
      __builtin_amdgcn_global_load_lds((gas_t)(const void*)src,
                                       (las_t)(void*)&As[buf][(wave * 4 + j) * 256],
                                       16, 0, 0);
    }
  };

  // --- B fp32 source (L2-resident 1 MB): lane reads expert row e=nt*16+l15,
  //     k = k_base + i*32 + quad*8 .. +8 ---
  const float* gW = W + (size_t)l15 * HDIM + k_base + quad * 8;

  f32x4 acc[2][4];
#pragma unroll
  for (int mt = 0; mt < 2; ++mt)
#pragma unroll
    for (int nt = 0; nt < 4; ++nt) acc[mt][nt] = (f32x4){0.f, 0.f, 0.f, 0.f};

  stageA(0, 0);

  for (int i = 0; i < NCHUNK; ++i) {
    const int buf = i & 1;
    // Drain this wave's own stageA(i) (only vmcnt ops outstanding at loop
    // top; for i>0 it has had a full chunk of flight).
    asm volatile("s_waitcnt vmcnt(0)" ::: "memory");
    __builtin_amdgcn_sched_barrier(0);  // rule #18: nothing hoists above

    // W loads FIRST (oldest vmcnt ops this chunk -> their dataflow wait is
    // vmcnt(4), leaving the 4 stageA DMAs below in flight; in-order retire)
    float4 bw[4][2];
#pragma unroll
    for (int nt = 0; nt < 4; ++nt) {
      const float* wp = gW + (size_t)(nt * 16) * HDIM + i * CHUNK;
      bw[nt][0] = *(const float4*)wp;
      bw[nt][1] = *(const float4*)(wp + 4);
    }
    // fragment reads: own-wave rows only (lgkm, independent of vmcnt)
    float4 a0[2], a1[2];
#pragma unroll
    for (int mt = 0; mt < 2; ++mt) {
      const int r = wm + mt * 16 + l15;
      const int rb = r * CHUNK;
      const int sw = r & 7;
      a0[mt] = *(const float4*)&As[buf][rb + ((2 * quad) ^ sw) * 4];
      a1[mt] = *(const float4*)&As[buf][rb + ((2 * quad + 1) ^ sw) * 4];
    }
    __builtin_amdgcn_sched_barrier(0);  // pin: W/ds loads stay above stageA

    if (i + 1 < NCHUNK) stageA(i + 1, buf ^ 1);  // full chunk of flight
    __builtin_amdgcn_sched_barrier(0);  // pin: stageA not sunk into compute

    short8 fa[2][3];
#pragma unroll
    for (int mt = 0; mt < 2; ++mt) {
      const float f[8] = {a0[mt].x, a0[mt].y, a0[mt].z, a0[mt].w,
                          a1[mt].x, a1[mt].y, a1[mt].z, a1[mt].w};
      int h[4], md[4], lo[4];
#pragma unroll
      for (int j = 0; j < 4; ++j) split2x3(f[2 * j], f[2 * j + 1], h[j], md[j], lo[j]);
      fa[mt][0] = pack_s8(h[0], h[1], h[2], h[3]);
      fa[mt][1] = pack_s8(md[0], md[1], md[2], md[3]);
      fa[mt][2] = pack_s8(lo[0], lo[1], lo[2], lo[3]);
    }

#pragma unroll
    for (int nt = 0; nt < 4; ++nt) {
      const float fb[8] = {bw[nt][0].x, bw[nt][0].y, bw[nt][0].z, bw[nt][0].w,
                           bw[nt][1].x, bw[nt][1].y, bw[nt][1].z, bw[nt][1].w};
      int h[4], md[4], lo[4];
#pragma unroll
      for (int j = 0; j < 4; ++j) split2x3(fb[2 * j], fb[2 * j + 1], h[j], md[j], lo[j]);
      const short8 bh = pack_s8(h[0], h[1], h[2], h[3]);
      const short8 bmid = pack_s8(md[0], md[1], md[2], md[3]);
      const short8 blo = pack_s8(lo[0], lo[1], lo[2], lo[3]);
#pragma unroll
      for (int mt = 0; mt < 2; ++mt) {
        f32x4 c = acc[mt][nt];
        c = __builtin_amdgcn_mfma_f32_16x16x32_bf16(fa[mt][0], bh, c, 0, 0, 0);
        c = __builtin_amdgcn_mfma_f32_16x16x32_bf16(fa[mt][0], bmid, c, 0, 0, 0);
        c = __builtin_amdgcn_mfma_f32_16x16x32_bf16(fa[mt][1], bh, c, 0, 0, 0);
        c = __builtin_amdgcn_mfma_f32_16x16x32_bf16(fa[mt][0], blo, c, 0, 0, 0);
        c = __builtin_amdgcn_mfma_f32_16x16x32_bf16(fa[mt][2], bh, c, 0, 0, 0);
        c = __builtin_amdgcn_mfma_f32_16x16x32_bf16(fa[mt][1], bmid, c, 0, 0, 0);
        acc[mt][nt] = c;
      }
    }
  }

#pragma unroll
  for (int mt = 0; mt < 2; ++mt)
#pragma unroll
    for (int nt = 0; nt < 4; ++nt)
#pragma unroll
      for (int r = 0; r < 4; ++r) {
        const int m = m_base + wm + mt * 16 + quad * 4 + r;
        const int n = nt * 16 + l15;
        if (atomic_mode) atomicAdd(&Lout[(size_t)m * NEXP + n], acc[mt][nt][r]);
        else Lout[(size_t)m * NEXP + n] = acc[mt][nt][r];
      }
}

// ---------------------------------------------------------------------------
// Top-k router v3 (unchanged — verified passing in round 5): wave-per-token-
// pair, both tokens' 32 slice loads prefetched to regs, interleaved reduce
// chains, single barrier, 32 auxbuf copies. No device-scope fences.
// ---------------------------------------------------------------------------
__global__ __launch_bounds__(256) void topk_k(const float* __restrict__ Lp, int nsl,
                                              float* __restrict__ out,
                                              float* __restrict__ auxbuf) {
  __shared__ float sl[2][4][64];
  __shared__ float s_aux[128];  // [0:64) prob sums, [64:128) pick counts
  const int tid = threadIdx.x;
  const int wave = tid >> 6, lane = tid & 63;
  if (tid < 128) s_aux[tid] = 0.f;

  const int t0 = (blockIdx.x * 4 + wave) * TPW;
  float x0 = 0.f, x1 = 0.f;
  if (nsl == KSPLIT) {
    float v[2][KSPLIT];
#pragma unroll
    for (int tok = 0; tok < 2; ++tok)
#pragma unroll
      for (int s = 0; s < KSPLIT; ++s)
        v[tok][s] = Lp[(size_t)s * (NTOK * NEXP) + (size_t)(t0 + tok) * NEXP + lane];
#pragma unroll
    for (int s = 0; s < KSPLIT; ++s) { x0 += v[0][s]; x1 += v[1][s]; }
  } else {
    for (int s = 0; s < nsl; ++s) {
      x0 += Lp[(size_t)s * (NTOK * NEXP) + (size_t)t0 * NEXP + lane];
      x1 += Lp[(size_t)s * (NTOK * NEXP) + (size_t)(t0 + 1) * NEXP + lane];
    }
  }
  sl[0][wave][lane] = x0;
  sl[1][wave][lane] = x1;

  float m0 = x0, m1 = x1;
#pragma unroll
  for (int off = 32; off >= 1; off >>= 1) {
    m0 = fmaxf(m0, __shfl_xor(m0, off, 64));
    m1 = fmaxf(m1, __shfl_xor(m1, off, 64));
  }
  const float e0 = __expf(x0 - m0), e1 = __expf(x1 - m1);
  float ss0 = e0, ss1 = e1;
#pragma unroll
  for (int off = 32; off >= 1; off >>= 1) {
    ss0 += __shfl_xor(ss0, off, 64);
    ss1 += __shfl_xor(ss1, off, 64);
  }
  const float p0 = e0 / ss0, p1 = e1 / ss1;

  __syncthreads();  // sl + s_aux-init visible

  int c0 = 0, c1 = 0;
#pragma unroll
  for (int c = 0; c < 4; ++c) {
#pragma unroll
    for (int tok = 0; tok < 2; ++tok) {
      const float4 w0 = *(const float4*)&sl[tok][wave][c * 16 + 0];
      const float4 w1 = *(const float4*)&sl[tok][wave][c * 16 + 4];
      const float4 w2 = *(const float4*)&sl[tok][wave][c * 16 + 8];
      const float4 w3 = *(const float4*)&sl[tok][wave][c * 16 + 12];
      const float xv[16] = {w0.x, w0.y, w0.z, w0.w, w1.x, w1.y, w1.z, w1.w,
                            w2.x, w2.y, w2.z, w2.w, w3.x, w3.y, w3.z, w3.w};
      const float xr = tok ? x1 : x0;
      int cc = 0;
#pragma unroll
      for (int j = 0; j < 16; ++j) {
        const int jj = c * 16 + j;
        cc += (xv[j] > xr) || (xv[j] == xr && jj < lane);
      }
      if (tok) c1 += cc; else c0 += cc;
    }
  }

  float tp0 = (c0 < 8) ? p0 : 0.f;
  float tp1 = (c1 < 8) ? p1 : 0.f;
  float ts0 = tp0, ts1 = tp1;
#pragma unroll
  for (int off = 32; off >= 1; off >>= 1) {
    ts0 += __shfl_xor(ts0, off, 64);
    ts1 += __shfl_xor(ts1, off, 64);
  }

  const float pv0 = __uint_as_float(
      (unsigned)__builtin_amdgcn_ds_permute(c0 << 2, (int)__float_as_uint(p0)));
  const int pi0 = __builtin_amdgcn_ds_permute(c0 << 2, lane);
  const float pv1 = __uint_as_float(
      (unsigned)__builtin_amdgcn_ds_permute(c1 << 2, (int)__float_as_uint(p1)));
  const int pi1 = __builtin_amdgcn_ds_permute(c1 << 2, lane);
  if (lane < 8) {
    out[(size_t)t0 * 8 + lane] = pv0 / ts0;
    out[(size_t)NTOK * 8 + (size_t)t0 * 8 + lane] = (float)pi0;
    out[(size_t)(t0 + 1) * 8 + lane] = pv1 / ts1;
    out[(size_t)NTOK * 8 + (size_t)(t0 + 1) * 8 + lane] = (float)pi1;
  }
  atomicAdd(&s_aux[lane], p0 + p1);
  const float cadd = (c0 < 8 ? 1.f : 0.f) + (c1 < 8 ? 1.f : 0.f);
  atomicAdd(&s_aux[64 + lane], cadd);

  __syncthreads();
  if (tid < 128)
    atomicAdd(&auxbuf[(blockIdx.x & (AUXCOPIES - 1)) * 128 + tid], s_aux[tid]);
}

// aux = E * sum_e (count_e/(T*K)) * (sumprob_e/T), over AUXCOPIES copies
__global__ void aux_k(const float* __restrict__ auxbuf, float* __restrict__ out) {
  const int e = threadIdx.x;  // 64 threads
  float p = 0.f, f = 0.f;
#pragma unroll
  for (int c = 0; c < AUXCOPIES; ++c) {
    p += auxbuf[c * 128 + e];
    f += auxbuf[c * 128 + 64 + e];
  }
  p *= (1.f / (float)NTOK);
  f *= (1.f / ((float)NTOK * 8.f));
  float v = f * p;
#pragma unroll
  for (int off = 32; off >= 1; off >>= 1) v += __shfl_xor(v, off, 64);
  if (e == 0) out[2 * NTOK * 8] = 64.f * v;
}

extern "C" void kernel_launch(void* const* d_in, const int* in_sizes, int n_in,
                              void* d_out, int out_size, void* d_ws, size_t ws_size,
                              hipStream_t stream) {
  const float* hidden = (const float*)d_in[0];  // 8192 x 4096 fp32
  const float* gate = (const float*)d_in[1];    // 64 x 4096 fp32
  float* out = (float*)d_out;                   // [w 65536 | idx 65536 | aux 1]
  float* ws = (float*)d_ws;
  float* auxbuf = ws;                           // AUXCOPIES x 128 floats
  float* slices = ws + AUXF;                    // KSPLIT x (8192*64) fp32 partials

  const size_t need = (size_t)AUXF * 4 + (size_t)KSPLIT * NTOK * NEXP * 4;
  const int atomic_mode = (ws_size < need) ? 1 : 0;
  const int nsl = atomic_mode ? 1 : KSPLIT;

  if (atomic_mode)  // fallback only; zeroes auxbuf + single-copy accumulator
    hipMemsetAsync(d_ws, 0, (size_t)AUXF * 4 + (size_t)NTOK * NEXP * 4, stream);

  gemm_k<<<dim3(64, KSPLIT), 256, 0, stream>>>(hidden, gate, slices, auxbuf,
                                               atomic_mode);
  topk_k<<<TOPK_BLOCKS, 256, 0, stream>>>(slices, nsl, out, auxbuf);
  aux_k<<<1, 64, 0, stream>>>(auxbuf, out);
}